// Round 7
// baseline (265.231 us; speedup 1.0000x reference)
//
#include <hip/hip_runtime.h>

// SimpleEncoder: LSTM(B=4096, S=512, I=3, H=16) + Linear(16->5) + clip(+-10)
//
// R7: MFMA + 4-wave cooperative workgroups.
//  - Workgroup = 16 batches, 4 waves; wave w owns units 4w..4w+3 (16 gate
//    rows, u-major order so C reg r == gate r: i,f,g,o).
//  - Per step per wave: 5 x mfma_f32_16x16x32_bf16:
//      Cg = A_xhi*Bx + A_xlo*Bx + A_hhi*Bh + A_hlo*Bh   (gates, fp32 acc)
//      Co = A_lin*Bh                                    (out projection)
//    All compounding weights/activations split hi/lo bf16 in the K dim
//    (K=32 = 16 units x {h_hi,h_lo}; A dwords duplicate W) -> recurrent
//    path exact to fp32-MFMA rounding.
//  - h exchanged across waves via double-buffered LDS dwords + ONE raw
//    "s_waitcnt lgkmcnt(0); s_barrier" per step (no vmcnt drain of the
//    fire-and-forget output stores).
//  - x staged in 64-step double-buffered LDS chunks (barriers make the
//    cross-wave staging visible for free).

#define TS 512
#define LOG2E 1.44269504088896340736f

typedef float f32x4v __attribute__((ext_vector_type(4)));
typedef short bf16x8 __attribute__((ext_vector_type(8)));

#define MFMA(A, B, C) __builtin_amdgcn_mfma_f32_16x16x32_bf16((A), (B), (C), 0, 0, 0)

__device__ __forceinline__ unsigned f2bf(float f) {  // RTN-even f32->bf16
  unsigned u = __float_as_uint(f);
  return (u + 0x7FFFu + ((u >> 16) & 1u)) >> 16;
}
__device__ __forceinline__ float bf2f(unsigned b) { return __uint_as_float(b << 16); }
// [bf16(f) | bf16(f - hi)<<16] : hi in even-k slot, lo in odd-k slot
__device__ __forceinline__ unsigned splitpack(float f) {
  unsigned hi = f2bf(f);
  unsigned lo = f2bf(f - bf2f(hi));
  return hi | (lo << 16);
}
__device__ __forceinline__ unsigned duppack(float f) {
  unsigned hi = f2bf(f);
  return hi | (hi << 16);
}
__device__ __forceinline__ bf16x8 frag(int a0, int a1, int a2, int a3) {
  int4 t{a0, a1, a2, a3};
  return __builtin_bit_cast(bf16x8, t);
}

__global__ __launch_bounds__(256)
__attribute__((amdgpu_waves_per_eu(1, 1)))
void lstm_enc_kernel(const float* __restrict__ x,
                     const float* __restrict__ W_ih,
                     const float* __restrict__ W_hh,
                     const float* __restrict__ b_ih,
                     const float* __restrict__ b_hh,
                     const float* __restrict__ W_lin,
                     const float* __restrict__ b_lin,
                     float* __restrict__ out) {
  const int tid = threadIdx.x;
  const int wv = tid >> 6;            // wave 0..3 -> units 4wv..4wv+3
  const int lane = tid & 63;
  const int n = lane & 15;            // batch column within workgroup
  const int q = lane >> 4;            // quad
  const int batch = blockIdx.x * 16 + n;

  __shared__ float4 xs[128][16];      // x staging (two 64-step chunks)
  __shared__ int2 hl2[2][144];        // h exchange (8B-aligned backing)
  int* hl = (int*)hl2;                // dword view: [par*288 + n*18 + unit]

  // ---- constant A fragments -------------------------------------------------
  // Block row m (=lane&15): unit un = 4wv + (m>>2), gate gt = m&3 (i,f,g,o).
  // Scales folded: i,f,o -> -log2e (sigmoid = rcp(1+exp2(z)));
  //                g     -> +2log2e (tanh = 1 - 2*rcp(1+exp2(z))).
  const int m = n;
  const int un = 4 * wv + (m >> 2);
  const int gt = m & 3;
  const int G = un + 16 * gt;
  const float sc = (gt == 2) ? 2.0f * LOG2E : -LOG2E;

  int a1[4], a2[4], a3[4], a4[4], a5[4];
#pragma unroll
  for (int r = 0; r < 3; ++r) {
    float w0 = W_ih[G * 3 + r] * sc;
    unsigned hi = f2bf(w0);
    unsigned lo = f2bf(w0 - bf2f(hi));
    a1[r] = (q == 0) ? (int)(hi | (hi << 16)) : 0;
    a2[r] = (q == 0) ? (int)(lo | (lo << 16)) : 0;
  }
  a1[3] = (q == 0) ? (int)splitpack((b_ih[G] + b_hh[G]) * sc) : 0;
  a2[3] = 0;
#pragma unroll
  for (int r = 0; r < 4; ++r) {
    const int u2 = 4 * q + r;
    float w0 = W_hh[G * 16 + u2] * sc;
    unsigned hi = f2bf(w0);
    unsigned lo = f2bf(w0 - bf2f(hi));
    a3[r] = (int)(hi | (hi << 16));
    a4[r] = (int)(lo | (lo << 16));
    a5[r] = (m < 5) ? (int)duppack(W_lin[m * 16 + u2]) : 0;
  }
  const bf16x8 A1 = frag(a1[0], a1[1], a1[2], a1[3]);
  const bf16x8 A2 = frag(a2[0], a2[1], a2[2], a2[3]);
  const bf16x8 A3 = frag(a3[0], a3[1], a3[2], a3[3]);
  const bf16x8 A4 = frag(a4[0], a4[1], a4[2], a4[3]);
  const bf16x8 A5 = frag(a5[0], a5[1], a5[2], a5[3]);
  const f32x4v z4 = {0.f, 0.f, 0.f, 0.f};

  // ---- output store mapping: wave w stores row w (q==0 lanes); wave 3's
  // q==1 lanes additionally store row 4 (C row m=4 lives at q=1, reg 0).
  const bool vst = (q == 0) || (wv == 3 && q == 1);
  const int col = (q == 0) ? wv : 4;
  const float blc = b_lin[col];
  const int osel = (q == 0) ? wv : 0;      // Co element to extract
  const bool sel1 = (osel & 1) != 0;
  const bool sel2 = (osel & 2) != 0;
  float* __restrict__ obp = out + (size_t)batch * (TS * 5) + col;

  // ---- x staging: lane tid covers batch bn = tid>>4, steps 4kq..4kq+3
  const int kq = tid & 15, bn = tid >> 4;
  const float* __restrict__ xcp =
      x + (size_t)(blockIdx.x * 16 + bn) * (TS * 3) + kq * 12;
  float4 q0 = *(const float4*)(xcp + 0);
  float4 q1 = *(const float4*)(xcp + 4);
  float4 q2 = *(const float4*)(xcp + 8);
  {
    const int rb = 4 * kq;               // chunk 0, parity 0
    xs[rb + 0][bn] = float4{q0.x, q0.y, q0.z, 0.f};
    xs[rb + 1][bn] = float4{q0.w, q1.x, q1.y, 0.f};
    xs[rb + 2][bn] = float4{q1.z, q1.w, q2.x, 0.f};
    xs[rb + 3][bn] = float4{q2.y, q2.z, q2.w, 0.f};
  }
  q0 = *(const float4*)(xcp + 192 + 0);  // chunk 1 in flight
  q1 = *(const float4*)(xcp + 192 + 4);
  q2 = *(const float4*)(xcp + 192 + 8);

  // h_{-1} = 0 into parity 0 (each lane owns (batch n, unit 4wv+q))
  hl[n * 18 + (4 * wv + q)] = 0;

  asm volatile("s_waitcnt lgkmcnt(0)\n\ts_barrier" ::: "memory");

  float4 xr[2];
  xr[0] = xs[0][n];
  xr[1] = xs[1][n];

  float c = 0.f;

#pragma unroll 2
  for (int t = 0; t < TS; ++t) {
    asm volatile("s_waitcnt lgkmcnt(0)\n\ts_barrier" ::: "memory");
    const int p = t & 1;

    // B_h: units 4q..4q+3 of batch n, parity p (each dword = [h_hi|h_lo])
    const int hbase = p * 288 + n * 18 + 4 * q;
    const int2 b0 = *(const int2*)&hl[hbase];
    const int2 b1 = *(const int2*)&hl[hbase + 2];
    const bf16x8 Bh = frag(b0.x, b0.y, b1.x, b1.y);

    // x_t (prefetched 2 steps ahead), refill the slot just freed
    const float4 xt = xr[p];
    xr[p] = xs[(t + 2) & 127][n];

    // B_x: k0..5 = x hi/lo pairs, k6..7 = 1.0 (bias row)
    const bf16x8 Bx =
        frag((int)splitpack(xt.x), (int)splitpack(xt.y),
             (int)splitpack(xt.z), 0x3F803F80);

    // gates (fp32 acc) + out projection (uses h_{t-1} -> out_{t-1})
    f32x4v Cg = z4;
    Cg = MFMA(A1, Bx, Cg);
    Cg = MFMA(A2, Bx, Cg);
    Cg = MFMA(A3, Bh, Cg);
    Cg = MFMA(A4, Bh, Cg);
    f32x4v Co = MFMA(A5, Bh, z4);

    if (t > 0) {
      const float o01 = sel1 ? Co.y : Co.x;
      const float o23 = sel1 ? Co.w : Co.z;
      float ov = (sel2 ? o23 : o01) + blc;
      ov = fminf(fmaxf(ov, -10.0f), 10.0f);
      if (vst) obp[(t - 1) * 5] = ov;
    }

    // chunk staging (uniform branches; barriers publish the writes)
    if ((t & 63) == 32 && t < 448) {
      const int rb = (((t >> 6) + 1) & 1) * 64 + 4 * kq;
      xs[rb + 0][bn] = float4{q0.x, q0.y, q0.z, 0.f};
      xs[rb + 1][bn] = float4{q0.w, q1.x, q1.y, 0.f};
      xs[rb + 2][bn] = float4{q1.z, q1.w, q2.x, 0.f};
      xs[rb + 3][bn] = float4{q2.y, q2.z, q2.w, 0.f};
    }
    if ((t & 63) == 40 && t < 384) {
      const float* xc = xcp + ((t >> 6) + 2) * 192;
      q0 = *(const float4*)(xc + 0);
      q1 = *(const float4*)(xc + 4);
      q2 = *(const float4*)(xc + 8);
    }

    // activations (reg r == gate r: i,f,g,o) and state update (1 unit/lane)
    const float ig = __builtin_amdgcn_rcpf(1.0f + __builtin_amdgcn_exp2f(Cg.x));
    const float fg = __builtin_amdgcn_rcpf(1.0f + __builtin_amdgcn_exp2f(Cg.y));
    const float sg = __builtin_amdgcn_rcpf(1.0f + __builtin_amdgcn_exp2f(Cg.z));
    const float og = __builtin_amdgcn_rcpf(1.0f + __builtin_amdgcn_exp2f(Cg.w));
    const float gg = fmaf(-2.0f, sg, 1.0f);     // tanh(g)
    c = fmaf(fg, c, ig * gg);
    const float tc = fmaf(-2.0f,
        __builtin_amdgcn_rcpf(1.0f + __builtin_amdgcn_exp2f((2.0f * LOG2E) * c)), 1.0f);
    const float h = og * tc;

    // publish h_t (hi/lo packed dword) into the other parity buffer
    hl[(p ^ 1) * 288 + n * 18 + (4 * wv + q)] = (int)splitpack(h);
  }

  // epilogue: out_{TS-1} from h_{TS-1} (sits in parity (TS)&1 == 0)
  asm volatile("s_waitcnt lgkmcnt(0)\n\ts_barrier" ::: "memory");
  {
    const int hbase = n * 18 + 4 * q;
    const int2 b0 = *(const int2*)&hl[hbase];
    const int2 b1 = *(const int2*)&hl[hbase + 2];
    const bf16x8 Bh = frag(b0.x, b0.y, b1.x, b1.y);
    const f32x4v Co = MFMA(A5, Bh, z4);
    const float o01 = sel1 ? Co.y : Co.x;
    const float o23 = sel1 ? Co.w : Co.z;
    float ov = (sel2 ? o23 : o01) + blc;
    ov = fminf(fmaxf(ov, -10.0f), 10.0f);
    if (vst) obp[(TS - 1) * 5] = ov;
  }
}

extern "C" void kernel_launch(void* const* d_in, const int* in_sizes, int n_in,
                              void* d_out, int out_size, void* d_ws, size_t ws_size,
                              hipStream_t stream) {
  const float* x     = (const float*)d_in[0];
  const float* W_ih  = (const float*)d_in[1];
  const float* W_hh  = (const float*)d_in[2];
  const float* b_ih  = (const float*)d_in[3];
  const float* b_hh  = (const float*)d_in[4];
  const float* W_lin = (const float*)d_in[5];
  const float* b_lin = (const float*)d_in[6];
  float* out = (float*)d_out;

  const int B = in_sizes[0] / (TS * 3);   // 4096
  const int grid = B / 16;                // 16 batches per 256-thread block
  lstm_enc_kernel<<<grid, 256, 0, stream>>>(x, W_ih, W_hh, b_ih, b_hh, W_lin, b_lin, out);
}